// Round 2
// baseline (715.293 us; speedup 1.0000x reference)
//
#include <hip/hip_runtime.h>

#define H 448
#define W 448
#define CIN 64
#define COUT 64
#define NBATCH 4
#define BS 14      // output block (block stride)
#define HW (H * W)
#define PITCH 40   // bf16 elems per pixel row in LDS A-tile (32 ch + 8 pad, 80B row, 16B aligned)

typedef __attribute__((ext_vector_type(8))) short short8;
typedef __attribute__((ext_vector_type(4))) float f32x4;

static __device__ __forceinline__ unsigned short f2bf(float f) {
  unsigned u = __float_as_uint(f);
  u += 0x7FFF + ((u >> 16) & 1);  // RNE
  return (unsigned short)(u >> 16);
}

// Pack weights into B-fragment order, channel-half major:
// wB[(((h*9 + tap)*4 + nt)*64 + lane)*8 + j] = bf16(W[k][n]),
//   k = quad*8 + j (channel within half), c = h*32 + k, n = nt*16 + (lane&15),
//   value = w[n][c][tap].
__global__ __launch_bounds__(256) void prep_wB(const float* __restrict__ w,
                                               unsigned short* __restrict__ wB) {
  int e = blockIdx.x * 256 + threadIdx.x;
  if (e >= 18 * 4 * 64 * 8) return;
  int j = e & 7, lane = (e >> 3) & 63, nt = (e >> 9) & 3, ht = e >> 11;
  int tap = ht % 9, h = ht / 9;
  int c = h * 32 + (lane >> 4) * 8 + j;
  int n = nt * 16 + (lane & 15);
  wB[e] = f2bf(w[(n * CIN + c) * 9 + tap]);
}

// 512 threads = 8 waves per 14x14 output block.
// Wave wv owns M-tiles {wv, wv+8} (13 tiles of 16 pixels; waves 5-7 own 1).
// acc[2][4] = 32 VGPRs -> __launch_bounds__(512,8) caps VGPR at 64
// -> 8 waves/SIMD = 32 waves/CU (4 blocks/CU; LDS 25.6KB/block fits 4x).
__global__ __launch_bounds__(512, 8) void sbnet_conv(
    const float* __restrict__ x, const float* __restrict__ mask,
    const unsigned short* __restrict__ wB, const float* __restrict__ bias,
    float* __restrict__ out) {
  // ---- bijective XCD swizzle: chunks of 64 work-items (= 2 block-rows) ----
  // hw id h -> xcd = h&7 (round-robin dispatch); give each XCD whole chunks so
  // horizontally adjacent blocks (which share 64B output lines and halo lines)
  // run on the SAME XCD back-to-back -> L2 write merge + halo L2 hits.
  const int hwid = blockIdx.x + (blockIdx.y << 5) + (blockIdx.z << 10);
  const int slot = hwid >> 3;
  const int wk = ((slot >> 6) << 9) + ((hwid & 7) << 6) + (slot & 63);
  const int bx = wk & 31, by = (wk >> 5) & 31, n = wk >> 10;
  const int t = threadIdx.x;

  // 25.6 KB: bf16 A-tile [256 pix][PITCH] (20.5KB) / f32 epilogue [32][200]
  __shared__ short tileS[12800];

  // ---- activity: max over 16x16 mask window (offset -1), -inf OOB ----
  {
    int p = 0;
    if (t < 256) {
      int wy = t >> 4, wx = t & 15;
      int my = by * BS - 1 + wy, mx = bx * BS - 1 + wx;
      if (my >= 0 && my < H && mx >= 0 && mx < W)
        p = mask[(n * H + my) * W + mx] > 0.5f;
    }
    if (!__syncthreads_or(p)) {
      for (int i = t; i < COUT * 98; i += 512) {
        int cc = i / 98;
        int pp = (i - cc * 98) * 2;
        int yy = pp / BS, xx = pp - yy * BS;
        *(float2*)(out + ((size_t)(n * COUT + cc) * H + by * BS + yy) * W +
                   bx * BS + xx) = make_float2(0.f, 0.f);
      }
      return;
    }
  }

  const int wv = t >> 6, lane = t & 63;
  const int quad = lane >> 4, lrow = lane & 15;
  const int nmt = (wv < 5) ? 2 : 1;

  // per-lane A base offsets (bf16 elems) for owned M-tiles
  int abase[2];
#pragma unroll
  for (int ti = 0; ti < 2; ++ti) {
    int m = (wv + 8 * ti) * 16 + lrow;
    if (m > 195) m = 195;  // clamp tail (broadcast, masked at store)
    int oy = m / BS, ox = m - oy * BS;
    abase[ti] = (oy * 16 + ox) * PITCH;
  }

  // staging geometry: thread handles pixel (t&255), 16 channels (t>>8 half)
  const int pix = t & 255, hb = t >> 8;
  const int iy = pix >> 4, ix = pix & 15;
  const int gy = by * BS - 1 + iy, gx = bx * BS - 1 + ix;
  const bool inb = (gy >= 0 && gy < H && gx >= 0 && gx < W);
  const float* xp = x + (size_t)n * CIN * HW + (inb ? (gy * W + gx) : 0);

  f32x4 acc[2][4];
#pragma unroll
  for (int ti = 0; ti < 2; ++ti)
#pragma unroll
    for (int nt = 0; nt < 4; ++nt) acc[ti][nt] = (f32x4){0.f, 0.f, 0.f, 0.f};

  const short8* wBl = (const short8*)wB + lane;

  // ---- main loop: 2 channel-halves x 9 taps, K=32 per MFMA ----
#pragma unroll 1
  for (int h = 0; h < 2; ++h) {
    if (h) __syncthreads();  // previous half's reads done before overwrite
    {
      int c0 = h * 32 + hb * 16;
#pragma unroll
      for (int g = 0; g < 2; ++g) {
        float v[8];
#pragma unroll
        for (int j = 0; j < 8; ++j)
          v[j] = inb ? xp[(size_t)(c0 + g * 8 + j) * HW] : 0.f;
        int4 pk;
        pk.x = (int)f2bf(v[0]) | ((int)f2bf(v[1]) << 16);
        pk.y = (int)f2bf(v[2]) | ((int)f2bf(v[3]) << 16);
        pk.z = (int)f2bf(v[4]) | ((int)f2bf(v[5]) << 16);
        pk.w = (int)f2bf(v[6]) | ((int)f2bf(v[7]) << 16);
        *(int4*)(tileS + pix * PITCH + hb * 16 + g * 8) = pk;
      }
    }
    __syncthreads();
#pragma unroll
    for (int tap = 0; tap < 9; ++tap) {
      short8 b[4];
#pragma unroll
      for (int nt = 0; nt < 4; ++nt)
        b[nt] = wBl[(((h * 9 + tap) * 4 + nt) << 6)];
      const int ky = tap / 3, kx = tap - 3 * ky;
      const int ko = (ky * 16 + kx) * PITCH + quad * 8;
#pragma unroll
      for (int ti = 0; ti < 2; ++ti) {
        if (ti < nmt) {
          short8 av = *(const short8*)(tileS + abase[ti] + ko);
#pragma unroll
          for (int nt = 0; nt < 4; ++nt)
            acc[ti][nt] = __builtin_amdgcn_mfma_f32_16x16x32_bf16(
                av, b[nt], acc[ti][nt], 0, 0, 0);
        }
      }
    }
  }

  // ---- epilogue: 2 passes of 32 couts, transpose via LDS, float2 stores ----
  float* ldsF = (float*)tileS;  // [32][200] f32 = 25.6 KB
#pragma unroll 1
  for (int p = 0; p < 2; ++p) {
    __syncthreads();  // A-tile reads / previous pass copy done
#pragma unroll
    for (int ti = 0; ti < 2; ++ti) {
      if (ti < nmt) {
        int mt = wv + 8 * ti;
        int m0 = mt * 16 + quad * 4;
        bool full = (mt < 12) || (quad == 0);  // tail tile: only quad 0 valid
        if (full) {
#pragma unroll
          for (int q2 = 0; q2 < 2; ++q2) {
            int nt = 2 * p + q2;
            float4 vv;
            vv.x = acc[ti][nt][0];
            vv.y = acc[ti][nt][1];
            vv.z = acc[ti][nt][2];
            vv.w = acc[ti][nt][3];
            *(float4*)(ldsF + (q2 * 16 + lrow) * 200 + m0) = vv;
          }
        }
      }
    }
    __syncthreads();
    for (int idx = t; idx < 32 * 98; idx += 512) {
      int co_l = idx / 98;
      int pp = (idx - co_l * 98) * 2;
      int cout = p * 32 + co_l;
      int oy = pp / BS, ox = pp - oy * BS;
      float2 r;
      float bi = bias[cout];
      r.x = ldsF[co_l * 200 + pp] + bi;
      r.y = ldsF[co_l * 200 + pp + 1] + bi;
      *(float2*)(out + ((size_t)(n * COUT + cout) * H + by * BS + oy) * W +
                 bx * BS + ox) = r;
    }
  }
}

extern "C" void kernel_launch(void* const* d_in, const int* in_sizes, int n_in,
                              void* d_out, int out_size, void* d_ws,
                              size_t ws_size, hipStream_t stream) {
  const float* x = (const float*)d_in[0];     // [4,64,448,448] f32
  const float* mask = (const float*)d_in[1];  // [4,1,448,448] f32
  const float* w = (const float*)d_in[2];     // [64,64,3,3] f32
  const float* bias = (const float*)d_in[3];  // [64] f32
  float* out = (float*)d_out;                 // [4,64,448,448] f32
  unsigned short* wB = (unsigned short*)d_ws; // 73728 B scratch

  prep_wB<<<dim3((18 * 4 * 64 * 8 + 255) / 256), 256, 0, stream>>>(w, wB);
  sbnet_conv<<<dim3(32, 32, NBATCH), 512, 0, stream>>>(x, mask, wB, bias, out);
}

// Round 4
// 394.794 us; speedup vs baseline: 1.8118x; 1.8118x over previous
//
#include <hip/hip_runtime.h>

#define H 448
#define W 448
#define CIN 64
#define COUT 64
#define NBATCH 4
#define BS 14      // output block (block stride)
#define HW (H * W)
#define PITCH 40   // bf16 elems per pixel row in LDS A-tile (32 ch + 8 pad, 80B row, 16B aligned)

typedef __attribute__((ext_vector_type(8))) short short8;
typedef __attribute__((ext_vector_type(4))) float f32x4;

static __device__ __forceinline__ unsigned short f2bf(float f) {
  unsigned u = __float_as_uint(f);
  u += 0x7FFF + ((u >> 16) & 1);  // RNE
  return (unsigned short)(u >> 16);
}

// Pack weights into B-fragment order, channel-half major:
// wB[(((h*9 + tap)*4 + nt)*64 + lane)*8 + j] = bf16(W[k][n]),
//   k = quad*8 + j (channel within half), c = h*32 + k, n = nt*16 + (lane&15),
//   value = w[n][c][tap].
__global__ __launch_bounds__(256) void prep_wB(const float* __restrict__ w,
                                               unsigned short* __restrict__ wB) {
  int e = blockIdx.x * 256 + threadIdx.x;
  if (e >= 18 * 4 * 64 * 8) return;
  int j = e & 7, lane = (e >> 3) & 63, nt = (e >> 9) & 3, ht = e >> 11;
  int tap = ht % 9, h = ht / 9;
  int c = h * 32 + (lane >> 4) * 8 + j;
  int n = nt * 16 + (lane & 15);
  wB[e] = f2bf(w[(n * CIN + c) * 9 + tap]);
}

// 512 threads = 8 waves = 4 M-groups x 2 N-groups per 14x14 output block.
// Wave (wm = wv&3, wn = wv>>2): M-tiles {wm+4i}, N-tiles {2wn, 2wn+1}.
// acc[4][2] = 32 regs; only 2 live B-fragments (8 regs) -> low pressure.
// __launch_bounds__(512,6) caps VGPR ~84 (no spill; R2's (512,8) cap=64 spilled:
// WRITE_SIZE tripled from scratch writeback).
__global__ __launch_bounds__(512, 6) void sbnet_conv(
    const float* __restrict__ x, const float* __restrict__ mask,
    const unsigned short* __restrict__ wB, const float* __restrict__ bias,
    float* __restrict__ out) {
  // ---- bijective XCD swizzle: chunks of 64 work-items (= 2 block-rows) ----
  // hw id h -> xcd = h&7 (round-robin dispatch); give each XCD whole chunks so
  // horizontally adjacent blocks (which share 64B output lines and halo lines)
  // run on the SAME XCD back-to-back -> L2 write merge + halo L2 hits.
  const int hwid = blockIdx.x + (blockIdx.y << 5) + (blockIdx.z << 10);
  const int slot = hwid >> 3;
  const int wk = ((slot >> 6) << 9) + ((hwid & 7) << 6) + (slot & 63);
  const int bx = wk & 31, by = (wk >> 5) & 31, n = wk >> 10;
  const int t = threadIdx.x;

  // 25.6 KB: bf16 A-tile [256 pix][PITCH] (20.5KB) / f32 epilogue [32][200]
  __shared__ short tileS[12800];

  // ---- activity: max over 16x16 mask window (offset -1), -inf OOB ----
  {
    int p = 0;
    if (t < 256) {
      int wy = t >> 4, wx = t & 15;
      int my = by * BS - 1 + wy, mx = bx * BS - 1 + wx;
      if (my >= 0 && my < H && mx >= 0 && mx < W)
        p = mask[(n * H + my) * W + mx] > 0.5f;
    }
    if (!__syncthreads_or(p)) {
      for (int i = t; i < COUT * 98; i += 512) {
        int cc = i / 98;
        int pp = (i - cc * 98) * 2;
        int yy = pp / BS, xx = pp - yy * BS;
        *(float2*)(out + ((size_t)(n * COUT + cc) * H + by * BS + yy) * W +
                   bx * BS + xx) = make_float2(0.f, 0.f);
      }
      return;
    }
  }

  const int wv = t >> 6, lane = t & 63;
  const int wm = wv & 3, wn = wv >> 2;
  const int quad = lane >> 4, lrow = lane & 15;
  const int nmt = (wm == 0) ? 4 : 3;  // 13 M-tiles: wm=0 owns {0,4,8,12}

  // per-lane A base offsets (bf16 elems) for owned M-tiles
  int abase[4];
#pragma unroll
  for (int ti = 0; ti < 4; ++ti) {
    int m = (wm + 4 * ti) * 16 + lrow;
    if (m > 195) m = 195;  // clamp tail (broadcast, masked at store)
    int oy = m / BS, ox = m - oy * BS;
    abase[ti] = (oy * 16 + ox) * PITCH;
  }

  // staging geometry: thread handles pixel (t&255), 16 channels (t>>8 half)
  const int pix = t & 255, hb = t >> 8;
  const int iy = pix >> 4, ix = pix & 15;
  const int gy = by * BS - 1 + iy, gx = bx * BS - 1 + ix;
  const bool inb = (gy >= 0 && gy < H && gx >= 0 && gx < W);
  const float* xp = x + (size_t)n * CIN * HW + (inb ? (gy * W + gx) : 0);

  f32x4 acc[4][2];
#pragma unroll
  for (int ti = 0; ti < 4; ++ti)
#pragma unroll
    for (int nt = 0; nt < 2; ++nt) acc[ti][nt] = (f32x4){0.f, 0.f, 0.f, 0.f};

  const short8* wBl = (const short8*)wB + lane;

  // ---- main loop: 2 channel-halves x 9 taps, K=32 per MFMA ----
#pragma unroll 1
  for (int h = 0; h < 2; ++h) {
    if (h) __syncthreads();  // previous half's reads done before overwrite
    {
      int c0 = h * 32 + hb * 16;
#pragma unroll
      for (int g = 0; g < 2; ++g) {
        float v[8];
#pragma unroll
        for (int j = 0; j < 8; ++j)
          v[j] = inb ? xp[(size_t)(c0 + g * 8 + j) * HW] : 0.f;
        int4 pk;
        pk.x = (int)f2bf(v[0]) | ((int)f2bf(v[1]) << 16);
        pk.y = (int)f2bf(v[2]) | ((int)f2bf(v[3]) << 16);
        pk.z = (int)f2bf(v[4]) | ((int)f2bf(v[5]) << 16);
        pk.w = (int)f2bf(v[6]) | ((int)f2bf(v[7]) << 16);
        *(int4*)(tileS + pix * PITCH + hb * 16 + g * 8) = pk;
      }
    }
    __syncthreads();
#pragma unroll
    for (int tap = 0; tap < 9; ++tap) {
      short8 b[2];
#pragma unroll
      for (int nt = 0; nt < 2; ++nt)
        b[nt] = wBl[(((h * 9 + tap) * 4 + wn * 2 + nt) << 6)];
      const int ky = tap / 3, kx = tap - 3 * ky;
      const int ko = (ky * 16 + kx) * PITCH + quad * 8;
#pragma unroll
      for (int ti = 0; ti < 4; ++ti) {
        if (ti < nmt) {
          short8 av = *(const short8*)(tileS + abase[ti] + ko);
#pragma unroll
          for (int nt = 0; nt < 2; ++nt)
            acc[ti][nt] = __builtin_amdgcn_mfma_f32_16x16x32_bf16(
                av, b[nt], acc[ti][nt], 0, 0, 0);
        }
      }
    }
  }

  // ---- epilogue: 2 passes of 32 couts (pass p = waves with wn==p) ----
  float* ldsF = (float*)tileS;  // [32][200] f32 = 25.6 KB
#pragma unroll 1
  for (int p = 0; p < 2; ++p) {
    __syncthreads();  // A-tile reads / previous pass copy done
    if (wn == p) {
#pragma unroll
      for (int ti = 0; ti < 4; ++ti) {
        if (ti < nmt) {
          int mt = wm + 4 * ti;
          int m0 = mt * 16 + quad * 4;
          bool full = (mt < 12) || (quad == 0);  // tail tile: only quad 0
          if (full) {
#pragma unroll
            for (int nt = 0; nt < 2; ++nt) {
              float4 vv;
              vv.x = acc[ti][nt][0];
              vv.y = acc[ti][nt][1];
              vv.z = acc[ti][nt][2];
              vv.w = acc[ti][nt][3];
              *(float4*)(ldsF + (nt * 16 + lrow) * 200 + m0) = vv;
            }
          }
        }
      }
    }
    __syncthreads();
    for (int idx = t; idx < 32 * 98; idx += 512) {
      int co_l = idx / 98;
      int pp = (idx - co_l * 98) * 2;
      int cout = p * 32 + co_l;
      int oy = pp / BS, ox = pp - oy * BS;
      float2 r;
      float bi = bias[cout];
      r.x = ldsF[co_l * 200 + pp] + bi;
      r.y = ldsF[co_l * 200 + pp + 1] + bi;
      *(float2*)(out + ((size_t)(n * COUT + cout) * H + by * BS + oy) * W +
                 bx * BS + ox) = r;
    }
  }
}

extern "C" void kernel_launch(void* const* d_in, const int* in_sizes, int n_in,
                              void* d_out, int out_size, void* d_ws,
                              size_t ws_size, hipStream_t stream) {
  const float* x = (const float*)d_in[0];     // [4,64,448,448] f32
  const float* mask = (const float*)d_in[1];  // [4,1,448,448] f32
  const float* w = (const float*)d_in[2];     // [64,64,3,3] f32
  const float* bias = (const float*)d_in[3];  // [64] f32
  float* out = (float*)d_out;                 // [4,64,448,448] f32
  unsigned short* wB = (unsigned short*)d_ws; // 73728 B scratch

  prep_wB<<<dim3((18 * 4 * 64 * 8 + 255) / 256), 256, 0, stream>>>(w, wB);
  sbnet_conv<<<dim3(32, 32, NBATCH), 512, 0, stream>>>(x, mask, wB, bias, out);
}